// Round 12
// baseline (134.798 us; speedup 1.0000x reference)
//
#include <hip/hip_runtime.h>
#include <math.h>

#pragma clang fp contract(off)

// ---------------------------------------------------------------------------
// Bit-exact fp32 emulation of the XLA-CPU (reassoc+contract) reference
// realization — VERIFIED PASSING (r10/r11: absmax 0.1875 < 0.2925, bits
// stable across restructurings). Arithmetic per problem is IDENTICAL to r11:
//   u = fma(s3,a1, mul(s2,b2)) + fma(s1,a3, -((s0*d4)/d))   [balanced tree]
// This round: 2 problems per thread (12288 -> 6144 threads, 96 blocks).
// The two chains interleave instruction-by-instruction, filling the LDS/
// divide/dependence latency bubbles that left r11 at 154 cyc/step vs the
// ~60 cyc issue floor. Op stream per problem unchanged => same output bits.
// ---------------------------------------------------------------------------

__device__ __forceinline__ float fmul32(float a, float b) {
  float d; asm("v_mul_f32 %0, %1, %2" : "=v"(d) : "v"(a), "v"(b)); return d;
}
__device__ __forceinline__ float fadd32(float a, float b) {
  float d; asm("v_add_f32 %0, %1, %2" : "=v"(d) : "v"(a), "v"(b)); return d;
}
__device__ __forceinline__ float fsub32(float a, float b) {
  float d; asm("v_sub_f32 %0, %1, %2" : "=v"(d) : "v"(a), "v"(b)); return d;
}
#define FMA32(a, b, c) __builtin_fmaf((a), (b), (c))

constexpr double RD64  = 100.0 / 1000.0;
constexpr double RD2   = RD64 * RD64;
constexpr float  KA32  = (float)(13.0 / 15.0 * RD2);
constexpr float  KB32  = (float)( 7.0 / 60.0 * RD2);
constexpr float  KC32  = (float)( 3.0 / 40.0 * RD2);
constexpr float  nKC32 = -KC32;
constexpr float  DRD32 = (float)(12.0 * RD64);
constexpr float  ISC32 = (float)(2.0 * RD64 / 45.0);
constexpr double Q64   = (100.0 - 0.1) / 999.0;     // np.linspace step

struct CS {                       // one chain's rolling state (stays in VGPRs)
  float s0, s1, s2, s3;
  float a1, a2, a3, b1, b2, d1, d2, d3, d4;
  float me;
  const float2* tvl;
};

__device__ __forceinline__ void cstep(CS& c, float tx, float ty) {
  float f  = fadd32(tx, fsub32(c.me, ty));
  float ai = FMA32(KA32, f, 2.0f);
  float bi = FMA32(KB32, f, -2.0f);
  float di = FMA32(nKC32, f, 1.0f);     // d = 1 - KC*f
  float w  = fmul32(c.s0, c.d4) / di;   // CR fp32 divide
  float m2 = fmul32(c.s2, c.b2);
  float t1 = FMA32(c.s3, c.a1, m2);
  float t2 = FMA32(c.s1, c.a3, -w);     // == fma(s1,a3, q) bitwise (c=-d)
  float u  = fadd32(t1, t2);
  c.d4 = c.d3; c.d3 = c.d2; c.d2 = c.d1; c.d1 = di;
  c.a3 = c.a2; c.a2 = c.a1; c.a1 = ai;
  c.b2 = c.b1; c.b1 = bi;
  c.s0 = c.s1; c.s1 = c.s2; c.s2 = c.s3; c.s3 = u;
}
__device__ __forceinline__ float fval(const CS& c, int idx) {
  float2 t = c.tvl[idx];
  return fadd32(t.x, fsub32(c.me, t.y));
}
__device__ __forceinline__ void seed(CS& c, float f0, float f1, float f2, float f3) {
  c.a1 = FMA32(KA32, f3, 2.0f);  c.a2 = FMA32(KA32, f2, 2.0f);  c.a3 = FMA32(KA32, f1, 2.0f);
  c.b1 = FMA32(KB32, f3, -2.0f); c.b2 = FMA32(KB32, f2, -2.0f);
  c.d1 = FMA32(nKC32, f3, 1.0f); c.d2 = FMA32(nKC32, f2, 1.0f);
  c.d3 = FMA32(nKC32, f1, 1.0f); c.d4 = FMA32(nKC32, f0, 1.0f);
}
__device__ __forceinline__ float panel(float f0, float f1, float f2, float f3, float f4) {
  float s1q = FMA32(f0, f0, fmul32(f4, f4));
  float s3q = FMA32(f1, f1, fmul32(f3, f3));
  float t   = FMA32(7.0f, s1q, fmul32(32.0f, s3q));
  float g   = FMA32(12.0f, f2, t);
  return fmul32(g, ISC32);
}
__device__ __forceinline__ float der5(float f4, float f3, float f2, float f1, float f0) {
  float m48 = fmul32(48.0f, f3);
  float d1  = FMA32(25.0f, f4, -m48);
  float d2  = FMA32(36.0f, f2, d1);
  float d3  = FMA32(-16.0f, f1, d2);
  float d4v = FMA32(3.0f, f0, d3);
  return d4v / DRD32;
}
__device__ __forceinline__ void fwd_init(CS& c, int l, const float* rr) {
  #pragma unroll
  for (int i = 0; i < 4; ++i) {           // powf ~CR via exact fp64 powers
    double rd = (double)rr[i];
    double r2 = rd * rd;
    float p1, p2;
    if (l == 0)      { p1 = rr[i];            p2 = (float)r2;        }
    else if (l == 1) { p1 = (float)r2;        p2 = (float)(r2 * rd); }
    else             { p1 = (float)(r2 * rd); p2 = (float)(r2 * r2); }
    float q  = p2 / (float)(2 * (l + 1));
    float u0 = fsub32(p1, q);
    if (i == 0) c.s0 = u0; else if (i == 1) c.s1 = u0;
    else if (i == 2) c.s2 = u0; else c.s3 = u0;
  }
  seed(c, fval(c, 0), fval(c, 1), fval(c, 2), fval(c, 3));
}
__device__ __forceinline__ void bwd_init(CS& c, int l, const float* rr, float e) {
  float sq = (float)sqrt((double)fabsf(e));
  #pragma unroll
  for (int i = 0; i < 4; ++i) {
    float x    = fmul32(rr[i], sq);
    float xl   = (l == 0) ? 1.0f : ((l == 1) ? x : fmul32(x, x));
    float fact = (l == 0) ? 1.0f : ((l == 1) ? 3.0f : 15.0f);
    float base = xl / fact;
    float h  = fmul32(x, x) / 2.0f;
    float c1 = (float)(2 * l + 3);
    float c2 = (float)(2 * (2 * l + 3) * (2 * l + 5));
    float t2 = fadd32(1.0f, h / c1);
    float series = fadd32(t2, fmul32(h, h) / c2);
    float ui = fmul32(fmul32(rr[i], base), series);
    if (i == 0) c.s0 = ui; else if (i == 1) c.s1 = ui;
    else if (i == 2) c.s2 = ui; else c.s3 = ui;
  }
  seed(c, fval(c, 999), fval(c, 998), fval(c, 997), fval(c, 996));
}

__global__ __launch_bounds__(64)
void eval_eig_kernel(const float* __restrict__ ein, float* __restrict__ out, int ntot) {
  __shared__ __align__(16) float2 tv[3][1000];   // { l(l+1)/r^2 , 1/r }
  __shared__ float gbA[224][64];                 // backward Simpson panels (A)
  __shared__ float gbB[224][64];                 // backward Simpson panels (B)

  for (int t = threadIdx.x; t < 3000; t += 64) {
    int li = t / 1000, i = t - li * 1000;
    double y = (double)i * Q64 + 0.1;
    float r  = (i == 999) ? 100.0f : (float)y;
    float r2 = fmul32(r, r);
    float num = (float)(li * (li + 1));
    tv[li][i] = make_float2(num / r2, 1.0f / r);
  }
  __syncthreads();

  const int gtid = blockIdx.x * 64 + threadIdx.x;
  const int pA = 2 * gtid;
  if (pA >= ntot) return;
  const bool hasB = (pA + 1) < ntot;
  const int pB = hasB ? (pA + 1) : pA;

  const int bA = pA / 3, lA = pA - bA * 3;
  const int bB = pB / 3, lB = pB - bB * 3;
  const float eA = ein[bA], eB = ein[bB];

  CS cA, cB;
  cA.me = -eA; cA.tvl = tv[lA];
  cB.me = -eB; cB.tvl = tv[lB];

  float rr[4];
  #pragma unroll
  for (int i = 0; i < 4; ++i) rr[i] = (float)((double)i * Q64 + 0.1);

  float lf_inA, lf_inB, integ_inA, integ_inB, u100A, u100B;

  // ====================== forward chains: u_zero, i = 4..100 =================
  {
    fwd_init(cA, lA, rr);
    fwd_init(cB, lB, rr);
    float p0A = cA.s0, p1A = cA.s1, p2A = cA.s2, p3A = cA.s3;
    float p0B = cB.s0, p1B = cB.s1, p2B = cB.s2, p3B = cB.s3;
    { float2 t = cA.tvl[4]; cstep(cA, t.x, t.y); }
    { float2 t = cB.tvl[4]; cstep(cB, t.x, t.y); }
    float accIA = panel(p0A, p1A, p2A, p3A, cA.s3); float pbA = cA.s3;
    float accIB = panel(p0B, p1B, p2B, p3B, cB.s3); float pbB = cB.s3;
    for (int k = 1; k < 24; ++k) {
      int base = 4 * k;
      float q1A, q2A, q3A, q4A, q1B, q2B, q3B, q4B;
      { float2 t = cA.tvl[base + 1]; cstep(cA, t.x, t.y); q1A = cA.s3; }
      { float2 t = cB.tvl[base + 1]; cstep(cB, t.x, t.y); q1B = cB.s3; }
      { float2 t = cA.tvl[base + 2]; cstep(cA, t.x, t.y); q2A = cA.s3; }
      { float2 t = cB.tvl[base + 2]; cstep(cB, t.x, t.y); q2B = cB.s3; }
      { float2 t = cA.tvl[base + 3]; cstep(cA, t.x, t.y); q3A = cA.s3; }
      { float2 t = cB.tvl[base + 3]; cstep(cB, t.x, t.y); q3B = cB.s3; }
      { float2 t = cA.tvl[base + 4]; cstep(cA, t.x, t.y); q4A = cA.s3; }
      { float2 t = cB.tvl[base + 4]; cstep(cB, t.x, t.y); q4B = cB.s3; }
      accIA = fadd32(accIA, panel(pbA, q1A, q2A, q3A, q4A)); pbA = q4A;
      accIB = fadd32(accIB, panel(pbB, q1B, q2B, q3B, q4B)); pbB = q4B;
    }
    float u96A = pbA, u96B = pbB, u97A, u97B, u98A, u98B, u99A, u99B;
    { float2 t = cA.tvl[97]; cstep(cA, t.x, t.y); u97A = cA.s3; }
    { float2 t = cB.tvl[97]; cstep(cB, t.x, t.y); u97B = cB.s3; }
    { float2 t = cA.tvl[98]; cstep(cA, t.x, t.y); u98A = cA.s3; }
    { float2 t = cB.tvl[98]; cstep(cB, t.x, t.y); u98B = cB.s3; }
    { float2 t = cA.tvl[99]; cstep(cA, t.x, t.y); u99A = cA.s3; }
    { float2 t = cB.tvl[99]; cstep(cB, t.x, t.y); u99B = cB.s3; }
    { float2 t = cA.tvl[100]; cstep(cA, t.x, t.y); u100A = cA.s3; }
    { float2 t = cB.tvl[100]; cstep(cB, t.x, t.y); u100B = cB.s3; }
    integ_inA = accIA; integ_inB = accIB;
    lf_inA = der5(u100A, u99A, u98A, u97A, u96A) / u100A;
    lf_inB = der5(u100B, u99B, u98B, u97B, u96B) / u100B;
  }

  // =============== backward chains: v[j], j=4..999, factor idx 999-j =========
  float lf_outA, lf_outB, integ_outA, integ_outB, v899A, v899B;
  {
    bwd_init(cA, lA, rr, eA);
    bwd_init(cB, lB, rr, eB);

    // Segment A: m = 995..896 (25 groups of 4, descending within group)
    for (int g = 0; g < 25; ++g) {
      int m0 = 992 - 4 * g;
      float4 la = *(const float4*)&cA.tvl[m0], ha = *(const float4*)&cA.tvl[m0 + 2];
      float4 lb = *(const float4*)&cB.tvl[m0], hb = *(const float4*)&cB.tvl[m0 + 2];
      cstep(cA, ha.z, ha.w); cstep(cB, hb.z, hb.w);
      cstep(cA, ha.x, ha.y); cstep(cB, hb.x, hb.y);
      cstep(cA, la.z, la.w); cstep(cB, lb.z, lb.w);
      cstep(cA, la.x, la.y); cstep(cB, lb.x, lb.y);
    }
    float r4A = cA.s3, r4B = cB.s3;       // u[896] opens panel 223

    float v900A, v901A, v902A, v903A, v900B, v901B, v902B, v903B;
    // Panel group: steps m=4P+3..4P for both chains, close panel P.
    #define BG2(P)                                                             \
      float4 la = *(const float4*)&cA.tvl[4 * (P)];                            \
      float4 ha = *(const float4*)&cA.tvl[4 * (P) + 2];                        \
      float4 lb = *(const float4*)&cB.tvl[4 * (P)];                            \
      float4 hb = *(const float4*)&cB.tvl[4 * (P) + 2];                        \
      cstep(cA, ha.z, ha.w); cstep(cB, hb.z, hb.w);                            \
      float f3A = cA.s3, f3B = cB.s3;                                          \
      cstep(cA, ha.x, ha.y); cstep(cB, hb.x, hb.y);                            \
      float f2A = cA.s3, f2B = cB.s3;                                          \
      cstep(cA, la.z, la.w); cstep(cB, lb.z, lb.w);                            \
      float f1A = cA.s3, f1B = cB.s3;                                          \
      cstep(cA, la.x, la.y); cstep(cB, lb.x, lb.y);                            \
      float f0A = cA.s3, f0B = cB.s3;                                          \
      gbA[(P)][threadIdx.x] = panel(f0A, f1A, f2A, f3A, r4A);                  \
      gbB[(P)][threadIdx.x] = panel(f0B, f1B, f2B, f3B, r4B);                  \
      r4A = f0A; r4B = f0B;

    // Segment B1: panels 223..26
    for (int p = 223; p >= 26; --p) { BG2(p); }
    // Panel 25: f0 = u[100] = u_infty[MR]
    { BG2(25); v899A = f0A; v899B = f0B; }
    // Panel 24: f3..f0 = u[99], u[98], u[97], u[96]
    { BG2(24);
      v900A = f3A; v901A = f2A; v902A = f1A; v903A = f0A;
      v900B = f3B; v901B = f2B; v902B = f1B; v903B = f0B; }
    // Segment B2: panels 23..0
    for (int p = 23; p >= 0; --p) { BG2(p); }
    #undef BG2

    // numpy .sum(0): sequential ascending panel order
    float aA = gbA[0][threadIdx.x], aB = gbB[0][threadIdx.x];
    for (int p = 1; p < 224; ++p) {
      aA = fadd32(aA, gbA[p][threadIdx.x]);
      aB = fadd32(aB, gbB[p][threadIdx.x]);
    }
    integ_outA = aA; integ_outB = aB;
    lf_outA = der5(v899A, v900A, v901A, v902A, v903A) / v899A;
    lf_outB = der5(v899B, v900B, v901B, v902B, v903B) / v899B;
  }

  // ======= final combine, fp32 in reference order =======
  {
    float uzsq = fmul32(u100A, u100A);
    float uisq = fmul32(v899A, v899A);
    float den  = fadd32(integ_inA / uzsq, integ_outA / uisq);
    float dnum = fsub32(lf_outA, lf_inA);
    float delta = (-dnum) / den;
    out[pA] = fadd32(eA, delta);
  }
  if (hasB) {
    float uzsq = fmul32(u100B, u100B);
    float uisq = fmul32(v899B, v899B);
    float den  = fadd32(integ_inB / uzsq, integ_outB / uisq);
    float dnum = fsub32(lf_outB, lf_inB);
    float delta = (-dnum) / den;
    out[pB] = fadd32(eB, delta);
  }
}

extern "C" void kernel_launch(void* const* d_in, const int* in_sizes, int n_in,
                              void* d_out, int out_size, void* d_ws, size_t ws_size,
                              hipStream_t stream) {
  const float* ein = (const float*)d_in[0];
  float* out = (float*)d_out;
  int ntot = in_sizes[0] * 3;                   // 4096 energies x 3 l-values
  int nthread = (ntot + 1) / 2;                 // 2 problems per thread
  int grid = (nthread + 63) / 64;               // 96 blocks
  eval_eig_kernel<<<dim3(grid), dim3(64), 0, stream>>>(ein, out, ntot);
}

// Round 13
// 74.594 us; speedup vs baseline: 1.8071x; 1.8071x over previous
//
#include <hip/hip_runtime.h>
#include <math.h>

#pragma clang fp contract(off)

// ---------------------------------------------------------------------------
// Bit-exact fp32 emulation of the XLA-CPU (reassoc+contract) reference
// realization — PASSING since r10 (absmax 0.1875 < 0.2925). r11 structure
// (192 blocks, 1 problem/thread, 73.4us). r12 lesson: fp32 '/' expands to the
// VCC-coupled v_div_scale/v_div_fmas sequence; VCC is hard-wired, so all
// divides in a wave SERIALIZE (~35cyc each) — that was the dominant stall.
// This round: chain divides use a VCC-free CR sequence (rcp + 2 Newton +
// Markstein fixup, 8 plain ops, pipelinable). CR except ~2^-25/op chance of
// 1-ulp deviation (expected <1 event over all 1.2e7 divides, each <=~0.03 at
// the output — inside the 0.10 margin). Init/combine divides stay native '/'.
// ---------------------------------------------------------------------------

__device__ __forceinline__ float fmul32(float a, float b) {
  float d; asm("v_mul_f32 %0, %1, %2" : "=v"(d) : "v"(a), "v"(b)); return d;
}
__device__ __forceinline__ float fadd32(float a, float b) {
  float d; asm("v_add_f32 %0, %1, %2" : "=v"(d) : "v"(a), "v"(b)); return d;
}
__device__ __forceinline__ float fsub32(float a, float b) {
  float d; asm("v_sub_f32 %0, %1, %2" : "=v"(d) : "v"(a), "v"(b)); return d;
}
#define FMA32(a, b, c) __builtin_fmaf((a), (b), (c))

// VCC-free correctly-rounding fp32 divide (benign range: d ~ 1, n finite).
// y2 = CR reciprocal w.h.p. (rcp 1ulp -> 2 Newton); Markstein fixup gives
// the CR quotient (exact when y2 is the CR reciprocal).
__device__ __forceinline__ float divcr(float n, float d) {
  float y0 = __builtin_amdgcn_rcpf(d);
  float e0 = FMA32(-d, y0, 1.0f);
  float y1 = FMA32(y0, e0, y0);
  float e1 = FMA32(-d, y1, 1.0f);
  float y2 = FMA32(y1, e1, y1);
  float q0 = fmul32(n, y2);
  float r  = FMA32(-d, q0, n);
  return FMA32(r, y2, q0);
}

// One chain step; q realized as -(s0*d_m4)/di via exact sign manipulation.
#define STEP_TV(TX, TY)                                                        \
  do {                                                                         \
    float f_   = fadd32((TX), fsub32(me, (TY)));                               \
    float ai_  = FMA32(KA32, f_, 2.0f);                                        \
    float bi_  = FMA32(KB32, f_, -2.0f);                                       \
    float di_  = FMA32(nKC32, f_, 1.0f);   /* d = 1 - KC*f */                  \
    float w_   = divcr(fmul32(s0, d_m4), di_);                                 \
    float m2_  = fmul32(s2, b_m2);                                             \
    float t1_  = FMA32(s3, a_m1, m2_);                                         \
    float t2_  = FMA32(s1, a_m3, -w_);     /* == fma(s1,a3, q) bitwise */      \
    float u_   = fadd32(t1_, t2_);                                             \
    d_m4 = d_m3; d_m3 = d_m2; d_m2 = d_m1; d_m1 = di_;                         \
    a_m3 = a_m2; a_m2 = a_m1; a_m1 = ai_;                                      \
    b_m2 = b_m1; b_m1 = bi_;                                                   \
    s0 = s1; s1 = s2; s2 = s3; s3 = u_;                                        \
  } while (0)

#define STEP(IDX) do { float2 tv_ = tvl[(IDX)]; STEP_TV(tv_.x, tv_.y); } while (0)

__global__ __launch_bounds__(64)
void eval_eig_kernel(const float* __restrict__ ein, float* __restrict__ out, int ntot) {
  constexpr double RD64  = 100.0 / 1000.0;
  constexpr double RD2   = RD64 * RD64;
  constexpr float  KA32  = (float)(13.0 / 15.0 * RD2);
  constexpr float  KB32  = (float)( 7.0 / 60.0 * RD2);
  constexpr float  KC32  = (float)( 3.0 / 40.0 * RD2);
  constexpr float  nKC32 = -KC32;
  constexpr float  DRD32 = (float)(12.0 * RD64);
  constexpr float  ISC32 = (float)(2.0 * RD64 / 45.0);
  constexpr double Q64   = (100.0 - 0.1) / 999.0;     // np.linspace step

  __shared__ __align__(16) float2 tv[3][1000];   // { l(l+1)/r^2 , 1/r }
  __shared__ float gbuf[224][64];                // backward Simpson panels

  for (int t = threadIdx.x; t < 3000; t += 64) {
    int li = t / 1000, i = t - li * 1000;
    double y = (double)i * Q64 + 0.1;
    float r  = (i == 999) ? 100.0f : (float)y;
    float r2 = fmul32(r, r);
    float num = (float)(li * (li + 1));
    tv[li][i] = make_float2(num / r2, 1.0f / r);
  }
  __syncthreads();

  const int tid = blockIdx.x * 64 + threadIdx.x;
  if (tid >= ntot) return;
  const int b = tid / 3;
  const int l = tid - b * 3;
  const float e  = ein[b];
  const float me = -e;
  const float2* __restrict__ tvl = tv[l];

  float rr[4];
  #pragma unroll
  for (int i = 0; i < 4; ++i) rr[i] = (float)((double)i * Q64 + 0.1);

  auto FVAL = [&](int idx) -> float {
    float2 t_ = tvl[idx];
    return fadd32(t_.x, fsub32(me, t_.y));
  };
  auto PANEL = [&](float f0, float f1, float f2v, float f3, float f4) -> float {
    float s1q = FMA32(f0, f0, fmul32(f4, f4));
    float s3q = FMA32(f1, f1, fmul32(f3, f3));
    float t   = FMA32(7.0f, s1q, fmul32(32.0f, s3q));
    float g   = FMA32(12.0f, f2v, t);
    return fmul32(g, ISC32);
  };
  auto DER5 = [&](float f4, float f3, float f2v, float f1, float f0) -> float {
    float m48 = fmul32(48.0f, f3);
    float d1  = FMA32(25.0f, f4, -m48);
    float d2  = FMA32(36.0f, f2v, d1);
    float d3  = FMA32(-16.0f, f1, d2);
    float d4v = FMA32(3.0f, f0, d3);
    return d4v / DRD32;
  };

  float lf_in, lf_out, integ_in, integ_out, u100v, v899;

  // ====================== forward chain: u_zero, i = 4..100 ==================
  {
    float s0, s1, s2, s3;
    #pragma unroll
    for (int i = 0; i < 4; ++i) {             // powf ~CR via exact fp64 powers
      double rd = (double)rr[i];
      double r2 = rd * rd;
      float p1, p2;
      if (l == 0)      { p1 = rr[i];            p2 = (float)r2;        }
      else if (l == 1) { p1 = (float)r2;        p2 = (float)(r2 * rd); }
      else             { p1 = (float)(r2 * rd); p2 = (float)(r2 * r2); }
      float q  = p2 / (float)(2 * (l + 1));
      float u0 = fsub32(p1, q);
      if (i == 0) s0 = u0; else if (i == 1) s1 = u0; else if (i == 2) s2 = u0; else s3 = u0;
    }
    float f0 = FVAL(0), f1 = FVAL(1), f2v = FVAL(2), f3 = FVAL(3);
    float a_m1 = FMA32(KA32, f3, 2.0f);
    float a_m2 = FMA32(KA32, f2v, 2.0f);
    float a_m3 = FMA32(KA32, f1, 2.0f);
    float b_m1 = FMA32(KB32, f3, -2.0f);
    float b_m2 = FMA32(KB32, f2v, -2.0f);
    float d_m1 = FMA32(nKC32, f3, 1.0f);
    float d_m2 = FMA32(nKC32, f2v, 1.0f);
    float d_m3 = FMA32(nKC32, f1, 1.0f);
    float d_m4 = FMA32(nKC32, f0, 1.0f);

    float p0 = s0, p1 = s1, p2 = s2, p3 = s3;
    STEP(4);
    float accI = PANEL(p0, p1, p2, p3, s3);   // panel 0; sequential .sum(0)
    float pb = s3;
    #pragma unroll 4
    for (int k = 1; k < 24; ++k) {
      int base = 4 * k;
      STEP(base + 1); float q1 = s3;
      STEP(base + 2); float q2 = s3;
      STEP(base + 3); float q3 = s3;
      STEP(base + 4); float q4 = s3;
      accI = fadd32(accI, PANEL(pb, q1, q2, q3, q4));
      pb = q4;
    }
    float u96 = pb;
    STEP(97);  float u97 = s3;
    STEP(98);  float u98 = s3;
    STEP(99);  float u99 = s3;
    STEP(100); u100v = s3;
    integ_in = accI;
    lf_in = DER5(u100v, u99, u98, u97, u96) / u100v;
  }

  // =============== backward chain: v[j], j=4..999, factor idx 999-j ==========
  // u_infty index m = 999-j runs 995..0. Branch-free 4-step groups.
  {
    float s0, s1, s2, s3;
    float sq = (float)sqrt((double)fabsf(e));
    #pragma unroll
    for (int i = 0; i < 4; ++i) {
      float x    = fmul32(rr[i], sq);
      float xl   = (l == 0) ? 1.0f : ((l == 1) ? x : fmul32(x, x));
      float fact = (l == 0) ? 1.0f : ((l == 1) ? 3.0f : 15.0f);
      float base = xl / fact;
      float h  = fmul32(x, x) / 2.0f;
      float c1 = (float)(2 * l + 3);
      float c2 = (float)(2 * (2 * l + 3) * (2 * l + 5));
      float t2 = fadd32(1.0f, h / c1);
      float series = fadd32(t2, fmul32(h, h) / c2);
      float ui = fmul32(fmul32(rr[i], base), series);
      if (i == 0) s0 = ui; else if (i == 1) s1 = ui; else if (i == 2) s2 = ui; else s3 = ui;
    }
    float f0 = FVAL(999), f1 = FVAL(998), f2v = FVAL(997), f3 = FVAL(996);
    float a_m1 = FMA32(KA32, f3, 2.0f);
    float a_m2 = FMA32(KA32, f2v, 2.0f);
    float a_m3 = FMA32(KA32, f1, 2.0f);
    float b_m1 = FMA32(KB32, f3, -2.0f);
    float b_m2 = FMA32(KB32, f2v, -2.0f);
    float d_m1 = FMA32(nKC32, f3, 1.0f);
    float d_m2 = FMA32(nKC32, f2v, 1.0f);
    float d_m3 = FMA32(nKC32, f1, 1.0f);
    float d_m4 = FMA32(nKC32, f0, 1.0f);

    // Segment A: m = 995..896 (25 groups of 4, descending within group).
    #pragma unroll 4
    for (int g = 0; g < 25; ++g) {
      int m0 = 992 - 4 * g;
      const float4* tq = (const float4*)&tvl[m0];
      float4 lo = tq[0], hi = tq[1];      // tvl[m0..m0+1], tvl[m0+2..m0+3]
      STEP_TV(hi.z, hi.w);                // m0+3
      STEP_TV(hi.x, hi.y);                // m0+2
      STEP_TV(lo.z, lo.w);                // m0+1
      STEP_TV(lo.x, lo.y);                // m0
    }
    float r4v = s3;                       // u[896] opens panel 223

    float v900, v901, v902, v903;
    // Panel group macro: steps m=4p+3..4p, close panel p, hand f0 to next.
    #define BGROUP(P)                                                          \
      const float4* tq = (const float4*)&tvl[4 * (P)];                         \
      float4 lo = tq[0], hi = tq[1];                                           \
      STEP_TV(hi.z, hi.w); float f3v = s3;                                     \
      STEP_TV(hi.x, hi.y); float f2w = s3;                                     \
      STEP_TV(lo.z, lo.w); float f1v = s3;                                     \
      STEP_TV(lo.x, lo.y); float f0v = s3;                                     \
      gbuf[(P)][threadIdx.x] = PANEL(f0v, f1v, f2w, f3v, r4v);                 \
      r4v = f0v;

    // Segment B1: panels 223..26
    #pragma unroll 4
    for (int p = 223; p >= 26; --p) { BGROUP(p); }
    // Panel 25: f0 = u[100] = u_infty[MR]
    { BGROUP(25); v899 = f0v; }
    // Panel 24: f3..f0 = u[99], u[98], u[97], u[96]
    { BGROUP(24); v900 = f3v; v901 = f2w; v902 = f1v; v903 = f0v; }
    // Segment B2: panels 23..0
    #pragma unroll 4
    for (int p = 23; p >= 0; --p) { BGROUP(p); }
    #undef BGROUP

    // numpy .sum(0): sequential ascending panel order
    float accO = gbuf[0][threadIdx.x];
    for (int p = 1; p < 224; ++p) accO = fadd32(accO, gbuf[p][threadIdx.x]);
    integ_out = accO;
    lf_out = DER5(v899, v900, v901, v902, v903) / v899;
  }

  // ======= final combine, fp32 in reference order =======
  float uzsq = fmul32(u100v, u100v);
  float uisq = fmul32(v899, v899);
  float den  = fadd32(integ_in / uzsq, integ_out / uisq);
  float dnum = fsub32(lf_out, lf_in);
  float delta = (-dnum) / den;
  out[tid] = fadd32(e, delta);
}

extern "C" void kernel_launch(void* const* d_in, const int* in_sizes, int n_in,
                              void* d_out, int out_size, void* d_ws, size_t ws_size,
                              hipStream_t stream) {
  const float* ein = (const float*)d_in[0];
  float* out = (float*)d_out;
  int ntot = in_sizes[0] * 3;             // 4096 energies x 3 l-values
  int grid = (ntot + 63) / 64;            // 192 blocks, 1 problem/thread
  eval_eig_kernel<<<dim3(grid), dim3(64), 0, stream>>>(ein, out, ntot);
}

// Round 14
// 63.077 us; speedup vs baseline: 2.1370x; 1.1826x over previous
//
#include <hip/hip_runtime.h>
#include <math.h>

#pragma clang fp contract(off)

// ---------------------------------------------------------------------------
// Bit-exact fp32 emulation of the XLA-CPU (reassoc+contract) reference
// realization — PASSING since r10 (absmax 0.1875, bit-stable r10-r13).
// Arithmetic tree per step (unchanged):
//   u = fadd( fma(s3,a1, mul(s2,b2)), fma(s1,a3, -divcr(mul(s0,d4), d)) )
// r13 lesson: inline-asm mul/add/sub pinned instruction order, exposing each
// step's ~16-op dependence chain on the in-order SIMD (~150cyc/step). This
// round: plain * / + / - under '#pragma clang fp contract(off)' — same single
// CR instructions (pragma kills contraction at IR level), but the scheduler
// may now software-pipeline across steps. divcr = rcp + 2x Newton + Markstein
// (VCC-free, CR w.h.p.; empirically bit-identical output since r13).
// ---------------------------------------------------------------------------

__device__ __forceinline__ float fmul32(float a, float b) { return a * b; }
__device__ __forceinline__ float fadd32(float a, float b) { return a + b; }
__device__ __forceinline__ float fsub32(float a, float b) { return a - b; }
#define FMA32(a, b, c) __builtin_fmaf((a), (b), (c))

// VCC-free correctly-rounding fp32 divide (benign range: d ~ 1, n finite).
__device__ __forceinline__ float divcr(float n, float d) {
  float y0 = __builtin_amdgcn_rcpf(d);
  float e0 = FMA32(-d, y0, 1.0f);
  float y1 = FMA32(y0, e0, y0);
  float e1 = FMA32(-d, y1, 1.0f);
  float y2 = FMA32(y1, e1, y1);
  float q0 = fmul32(n, y2);
  float r  = FMA32(-d, q0, n);
  return FMA32(r, y2, q0);
}

// One chain step; q realized as -(s0*d_m4)/di via exact sign manipulation.
#define STEP_TV(TX, TY)                                                        \
  do {                                                                         \
    float f_   = fadd32((TX), fsub32(me, (TY)));                               \
    float ai_  = FMA32(KA32, f_, 2.0f);                                        \
    float bi_  = FMA32(KB32, f_, -2.0f);                                       \
    float di_  = FMA32(nKC32, f_, 1.0f);   /* d = 1 - KC*f */                  \
    float w_   = divcr(fmul32(s0, d_m4), di_);                                 \
    float m2_  = fmul32(s2, b_m2);                                             \
    float t1_  = FMA32(s3, a_m1, m2_);                                         \
    float t2_  = FMA32(s1, a_m3, -w_);     /* == fma(s1,a3, q) bitwise */      \
    float u_   = fadd32(t1_, t2_);                                             \
    d_m4 = d_m3; d_m3 = d_m2; d_m2 = d_m1; d_m1 = di_;                         \
    a_m3 = a_m2; a_m2 = a_m1; a_m1 = ai_;                                      \
    b_m2 = b_m1; b_m1 = bi_;                                                   \
    s0 = s1; s1 = s2; s2 = s3; s3 = u_;                                        \
  } while (0)

#define STEP(IDX) do { float2 tv_ = tvl[(IDX)]; STEP_TV(tv_.x, tv_.y); } while (0)

__global__ __launch_bounds__(64)
void eval_eig_kernel(const float* __restrict__ ein, float* __restrict__ out, int ntot) {
  constexpr double RD64  = 100.0 / 1000.0;
  constexpr double RD2   = RD64 * RD64;
  constexpr float  KA32  = (float)(13.0 / 15.0 * RD2);
  constexpr float  KB32  = (float)( 7.0 / 60.0 * RD2);
  constexpr float  KC32  = (float)( 3.0 / 40.0 * RD2);
  constexpr float  nKC32 = -KC32;
  constexpr float  DRD32 = (float)(12.0 * RD64);
  constexpr float  ISC32 = (float)(2.0 * RD64 / 45.0);
  constexpr double Q64   = (100.0 - 0.1) / 999.0;     // np.linspace step

  __shared__ __align__(16) float2 tv[3][1000];   // { l(l+1)/r^2 , 1/r }
  __shared__ float gbuf[224][64];                // backward Simpson panels

  for (int t = threadIdx.x; t < 3000; t += 64) {
    int li = t / 1000, i = t - li * 1000;
    double y = (double)i * Q64 + 0.1;
    float r  = (i == 999) ? 100.0f : (float)y;
    float r2 = fmul32(r, r);
    float num = (float)(li * (li + 1));
    tv[li][i] = make_float2(num / r2, 1.0f / r);
  }
  __syncthreads();

  const int tid = blockIdx.x * 64 + threadIdx.x;
  if (tid >= ntot) return;
  const int b = tid / 3;
  const int l = tid - b * 3;
  const float e  = ein[b];
  const float me = -e;
  const float2* __restrict__ tvl = tv[l];

  float rr[4];
  #pragma unroll
  for (int i = 0; i < 4; ++i) rr[i] = (float)((double)i * Q64 + 0.1);

  auto FVAL = [&](int idx) -> float {
    float2 t_ = tvl[idx];
    return fadd32(t_.x, fsub32(me, t_.y));
  };
  auto PANEL = [&](float f0, float f1, float f2v, float f3, float f4) -> float {
    float s1q = FMA32(f0, f0, fmul32(f4, f4));
    float s3q = FMA32(f1, f1, fmul32(f3, f3));
    float t   = FMA32(7.0f, s1q, fmul32(32.0f, s3q));
    float g   = FMA32(12.0f, f2v, t);
    return fmul32(g, ISC32);
  };
  auto DER5 = [&](float f4, float f3, float f2v, float f1, float f0) -> float {
    float m48 = fmul32(48.0f, f3);
    float d1  = FMA32(25.0f, f4, -m48);
    float d2  = FMA32(36.0f, f2v, d1);
    float d3  = FMA32(-16.0f, f1, d2);
    float d4v = FMA32(3.0f, f0, d3);
    return d4v / DRD32;
  };

  float lf_in, lf_out, integ_in, integ_out, u100v, v899;

  // ====================== forward chain: u_zero, i = 4..100 ==================
  {
    float s0, s1, s2, s3;
    #pragma unroll
    for (int i = 0; i < 4; ++i) {             // powf ~CR via exact fp64 powers
      double rd = (double)rr[i];
      double r2 = rd * rd;
      float p1, p2;
      if (l == 0)      { p1 = rr[i];            p2 = (float)r2;        }
      else if (l == 1) { p1 = (float)r2;        p2 = (float)(r2 * rd); }
      else             { p1 = (float)(r2 * rd); p2 = (float)(r2 * r2); }
      float q  = p2 / (float)(2 * (l + 1));
      float u0 = fsub32(p1, q);
      if (i == 0) s0 = u0; else if (i == 1) s1 = u0; else if (i == 2) s2 = u0; else s3 = u0;
    }
    float f0 = FVAL(0), f1 = FVAL(1), f2v = FVAL(2), f3 = FVAL(3);
    float a_m1 = FMA32(KA32, f3, 2.0f);
    float a_m2 = FMA32(KA32, f2v, 2.0f);
    float a_m3 = FMA32(KA32, f1, 2.0f);
    float b_m1 = FMA32(KB32, f3, -2.0f);
    float b_m2 = FMA32(KB32, f2v, -2.0f);
    float d_m1 = FMA32(nKC32, f3, 1.0f);
    float d_m2 = FMA32(nKC32, f2v, 1.0f);
    float d_m3 = FMA32(nKC32, f1, 1.0f);
    float d_m4 = FMA32(nKC32, f0, 1.0f);

    float p0 = s0, p1 = s1, p2 = s2, p3 = s3;
    STEP(4);
    float accI = PANEL(p0, p1, p2, p3, s3);   // panel 0; sequential .sum(0)
    float pb = s3;
    #pragma unroll 4
    for (int k = 1; k < 24; ++k) {
      int base = 4 * k;
      STEP(base + 1); float q1 = s3;
      STEP(base + 2); float q2 = s3;
      STEP(base + 3); float q3 = s3;
      STEP(base + 4); float q4 = s3;
      accI = fadd32(accI, PANEL(pb, q1, q2, q3, q4));
      pb = q4;
    }
    float u96 = pb;
    STEP(97);  float u97 = s3;
    STEP(98);  float u98 = s3;
    STEP(99);  float u99 = s3;
    STEP(100); u100v = s3;
    integ_in = accI;
    lf_in = DER5(u100v, u99, u98, u97, u96) / u100v;
  }

  // =============== backward chain: v[j], j=4..999, factor idx 999-j ==========
  // u_infty index m = 999-j runs 995..0. Branch-free 4-step groups.
  {
    float s0, s1, s2, s3;
    float sq = (float)sqrt((double)fabsf(e));
    #pragma unroll
    for (int i = 0; i < 4; ++i) {
      float x    = fmul32(rr[i], sq);
      float xl   = (l == 0) ? 1.0f : ((l == 1) ? x : fmul32(x, x));
      float fact = (l == 0) ? 1.0f : ((l == 1) ? 3.0f : 15.0f);
      float base = xl / fact;
      float h  = fmul32(x, x) / 2.0f;
      float c1 = (float)(2 * l + 3);
      float c2 = (float)(2 * (2 * l + 3) * (2 * l + 5));
      float t2 = fadd32(1.0f, h / c1);
      float series = fadd32(t2, fmul32(h, h) / c2);
      float ui = fmul32(fmul32(rr[i], base), series);
      if (i == 0) s0 = ui; else if (i == 1) s1 = ui; else if (i == 2) s2 = ui; else s3 = ui;
    }
    float f0 = FVAL(999), f1 = FVAL(998), f2v = FVAL(997), f3 = FVAL(996);
    float a_m1 = FMA32(KA32, f3, 2.0f);
    float a_m2 = FMA32(KA32, f2v, 2.0f);
    float a_m3 = FMA32(KA32, f1, 2.0f);
    float b_m1 = FMA32(KB32, f3, -2.0f);
    float b_m2 = FMA32(KB32, f2v, -2.0f);
    float d_m1 = FMA32(nKC32, f3, 1.0f);
    float d_m2 = FMA32(nKC32, f2v, 1.0f);
    float d_m3 = FMA32(nKC32, f1, 1.0f);
    float d_m4 = FMA32(nKC32, f0, 1.0f);

    // Segment A: m = 995..896 (25 groups of 4, descending within group).
    #pragma unroll 4
    for (int g = 0; g < 25; ++g) {
      int m0 = 992 - 4 * g;
      const float4* tq = (const float4*)&tvl[m0];
      float4 lo = tq[0], hi = tq[1];      // tvl[m0..m0+1], tvl[m0+2..m0+3]
      STEP_TV(hi.z, hi.w);                // m0+3
      STEP_TV(hi.x, hi.y);                // m0+2
      STEP_TV(lo.z, lo.w);                // m0+1
      STEP_TV(lo.x, lo.y);                // m0
    }
    float r4v = s3;                       // u[896] opens panel 223

    float v900, v901, v902, v903;
    // Panel group macro: steps m=4p+3..4p, close panel p, hand f0 to next.
    #define BGROUP(P)                                                          \
      const float4* tq = (const float4*)&tvl[4 * (P)];                         \
      float4 lo = tq[0], hi = tq[1];                                           \
      STEP_TV(hi.z, hi.w); float f3v = s3;                                     \
      STEP_TV(hi.x, hi.y); float f2w = s3;                                     \
      STEP_TV(lo.z, lo.w); float f1v = s3;                                     \
      STEP_TV(lo.x, lo.y); float f0v = s3;                                     \
      gbuf[(P)][threadIdx.x] = PANEL(f0v, f1v, f2w, f3v, r4v);                 \
      r4v = f0v;

    // Segment B1: panels 223..26
    #pragma unroll 4
    for (int p = 223; p >= 26; --p) { BGROUP(p); }
    // Panel 25: f0 = u[100] = u_infty[MR]
    { BGROUP(25); v899 = f0v; }
    // Panel 24: f3..f0 = u[99], u[98], u[97], u[96]
    { BGROUP(24); v900 = f3v; v901 = f2w; v902 = f1v; v903 = f0v; }
    // Segment B2: panels 23..0
    #pragma unroll 4
    for (int p = 23; p >= 0; --p) { BGROUP(p); }
    #undef BGROUP

    // numpy .sum(0): sequential ascending panel order
    float accO = gbuf[0][threadIdx.x];
    for (int p = 1; p < 224; ++p) accO = fadd32(accO, gbuf[p][threadIdx.x]);
    integ_out = accO;
    lf_out = DER5(v899, v900, v901, v902, v903) / v899;
  }

  // ======= final combine, fp32 in reference order =======
  float uzsq = fmul32(u100v, u100v);
  float uisq = fmul32(v899, v899);
  float den  = fadd32(integ_in / uzsq, integ_out / uisq);
  float dnum = fsub32(lf_out, lf_in);
  float delta = (-dnum) / den;
  out[tid] = fadd32(e, delta);
}

extern "C" void kernel_launch(void* const* d_in, const int* in_sizes, int n_in,
                              void* d_out, int out_size, void* d_ws, size_t ws_size,
                              hipStream_t stream) {
  const float* ein = (const float*)d_in[0];
  float* out = (float*)d_out;
  int ntot = in_sizes[0] * 3;             // 4096 energies x 3 l-values
  int grid = (ntot + 63) / 64;            // 192 blocks, 1 problem/thread
  eval_eig_kernel<<<dim3(grid), dim3(64), 0, stream>>>(ein, out, ntot);
}